// Round 1
// baseline (1015.274 us; speedup 1.0000x reference)
//
#include <hip/hip_runtime.h>

#define B_ROWS 32768
#define H 256
#define NBLK 4
#define CC 32

#define BM 64
#define BN 64
#define BK 32

// ---------------------------------------------------------------------------
// Fold conv (SAME, width 25, 3 filters) into the following GEMM weights:
// wceff[i][c*32+j][h'] = sum_k f_c[k] * Wc_c[i][j][h'+12-k]  (clipped to [0,256))
// bceff[i][c*32+j]     = bc_c[i][j]
// ---------------------------------------------------------------------------
__global__ __launch_bounds__(256) void precompute_wceff(
    const float* __restrict__ filters,
    const float* __restrict__ Wc1, const float* __restrict__ Wc2, const float* __restrict__ Wc3,
    const float* __restrict__ bc1, const float* __restrict__ bc2, const float* __restrict__ bc3,
    float* __restrict__ wceff, float* __restrict__ bceff)
{
    int idx = blockIdx.x * 256 + threadIdx.x;      // 4*96*256 = 98304 total
    if (idx >= NBLK * 96 * H) return;
    int h   = idx & 255;
    int j96 = (idx >> 8) % 96;
    int i   = idx / (96 * H);
    int c   = j96 >> 5, j = j96 & 31;
    const float* Wc = (c == 0) ? Wc1 : (c == 1) ? Wc2 : Wc3;
    const float* f  = filters + c * 25;
    float acc = 0.f;
    #pragma unroll
    for (int k = 0; k < 25; ++k) {
        int hh = h + 12 - k;
        if (hh >= 0 && hh < H) acc += f[k] * Wc[i * CC * H + j * H + hh];
    }
    wceff[idx] = acc;
    if (h == 0) {
        const float* bc = (c == 0) ? bc1 : (c == 1) ? bc2 : bc3;
        bceff[i * 96 + j96] = bc[i * CC + j];
    }
}

// ---------------------------------------------------------------------------
// C[M,N] = act( A[M,K] @ W[N,K]^T + bias[N] ) (+ res[M,256])
// A row stride == K. res (when non-null) has row stride 256.
// actmode: 0=none, 1=prelu(*alpha_ptr), 2=lrelu(0.1)
// M = 32768 (multiple of BM). K multiple of BK. N guarded.
// ---------------------------------------------------------------------------
__global__ __launch_bounds__(256) void gemm_nt(
    const float* __restrict__ A, const float* __restrict__ W,
    const float* __restrict__ bias, const float* __restrict__ res,
    float* __restrict__ C, int N, int K,
    int actmode, const float* __restrict__ alpha_ptr)
{
    __shared__ float As[BK][BM + 4];
    __shared__ float Ws[BK][BN + 4];
    const int bm  = blockIdx.x * BM;
    const int bn  = blockIdx.y * BN;
    const int tid = threadIdx.x;
    const int lr  = tid >> 3;            // 0..31 : row-in-tile for loads
    const int lk  = (tid & 7) << 2;      // 0,4,...,28 : k-offset for loads
    const int tm  = (tid >> 4) << 2;     // 0..60
    const int tn  = (tid & 15) << 2;     // 0..60
    float acc[4][4] = {};

    for (int k0 = 0; k0 < K; k0 += BK) {
        float4 a0 = *(const float4*)(A + (size_t)(bm + lr) * K + k0 + lk);
        float4 a1 = *(const float4*)(A + (size_t)(bm + lr + 32) * K + k0 + lk);
        float4 w0 = {0.f, 0.f, 0.f, 0.f}, w1 = {0.f, 0.f, 0.f, 0.f};
        if (bn + lr < N)      w0 = *(const float4*)(W + (size_t)(bn + lr) * K + k0 + lk);
        if (bn + lr + 32 < N) w1 = *(const float4*)(W + (size_t)(bn + lr + 32) * K + k0 + lk);

        __syncthreads();   // protect previous iteration's LDS reads
        As[lk + 0][lr] = a0.x; As[lk + 1][lr] = a0.y; As[lk + 2][lr] = a0.z; As[lk + 3][lr] = a0.w;
        As[lk + 0][lr + 32] = a1.x; As[lk + 1][lr + 32] = a1.y; As[lk + 2][lr + 32] = a1.z; As[lk + 3][lr + 32] = a1.w;
        Ws[lk + 0][lr] = w0.x; Ws[lk + 1][lr] = w0.y; Ws[lk + 2][lr] = w0.z; Ws[lk + 3][lr] = w0.w;
        Ws[lk + 0][lr + 32] = w1.x; Ws[lk + 1][lr + 32] = w1.y; Ws[lk + 2][lr + 32] = w1.z; Ws[lk + 3][lr + 32] = w1.w;
        __syncthreads();

        #pragma unroll
        for (int k = 0; k < BK; ++k) {
            float4 av = *(const float4*)(&As[k][tm]);
            float4 wv = *(const float4*)(&Ws[k][tn]);
            acc[0][0] += av.x * wv.x; acc[0][1] += av.x * wv.y; acc[0][2] += av.x * wv.z; acc[0][3] += av.x * wv.w;
            acc[1][0] += av.y * wv.x; acc[1][1] += av.y * wv.y; acc[1][2] += av.y * wv.z; acc[1][3] += av.y * wv.w;
            acc[2][0] += av.z * wv.x; acc[2][1] += av.z * wv.y; acc[2][2] += av.z * wv.z; acc[2][3] += av.z * wv.w;
            acc[3][0] += av.w * wv.x; acc[3][1] += av.w * wv.y; acc[3][2] += av.w * wv.z; acc[3][3] += av.w * wv.w;
        }
    }

    const float alpha = alpha_ptr ? *alpha_ptr : 0.f;
    #pragma unroll
    for (int i2 = 0; i2 < 4; ++i2) {
        const int r = bm + tm + i2;
        #pragma unroll
        for (int j2 = 0; j2 < 4; ++j2) {
            const int cc = bn + tn + j2;
            if (cc < N) {
                float v = acc[i2][j2] + bias[cc];
                if (actmode == 1)      v = (v >= 0.f) ? v : alpha * v;
                else if (actmode == 2) v = (v >= 0.f) ? v : 0.1f * v;
                if (res) v += res[(size_t)r * H + cc];
                C[(size_t)r * N + cc] = v;
            }
        }
    }
}

// ---------------------------------------------------------------------------
// LayerNorm over last dim (256), one wave per row, 4 rows per block.
// ---------------------------------------------------------------------------
__global__ __launch_bounds__(256) void ln_rows(
    const float* __restrict__ in, float* __restrict__ out,
    const float* __restrict__ g, const float* __restrict__ b)
{
    const int lane = threadIdx.x & 63;
    const int row  = blockIdx.x * 4 + (threadIdx.x >> 6);
    const float4 v = *(const float4*)(in + (size_t)row * H + lane * 4);
    float s = v.x + v.y + v.z + v.w;
    #pragma unroll
    for (int off = 32; off; off >>= 1) s += __shfl_xor(s, off);
    const float mean = s * (1.f / 256.f);
    const float dx = v.x - mean, dy = v.y - mean, dz = v.z - mean, dw = v.w - mean;
    float q = dx * dx + dy * dy + dz * dz + dw * dw;
    #pragma unroll
    for (int off = 32; off; off >>= 1) q += __shfl_xor(q, off);
    const float rstd = rsqrtf(q * (1.f / 256.f) + 1e-5f);
    const float4 gg = *(const float4*)(g + lane * 4);
    const float4 bb = *(const float4*)(b + lane * 4);
    float4 o;
    o.x = dx * rstd * gg.x + bb.x;
    o.y = dy * rstd * gg.y + bb.y;
    o.z = dz * rstd * gg.z + bb.z;
    o.w = dw * rstd * gg.w + bb.w;
    *(float4*)(out + (size_t)row * H + lane * 4) = o;
}

// ---------------------------------------------------------------------------
// Final: out[r] = in[r,:] . Wout + bout   (one wave per row)
// ---------------------------------------------------------------------------
__global__ __launch_bounds__(256) void matvec_out(
    const float* __restrict__ in, const float* __restrict__ w,
    const float* __restrict__ bout, float* __restrict__ outp)
{
    const int lane = threadIdx.x & 63;
    const int row  = blockIdx.x * 4 + (threadIdx.x >> 6);
    const float4 v  = *(const float4*)(in + (size_t)row * H + lane * 4);
    const float4 ww = *(const float4*)(w + lane * 4);
    float s = v.x * ww.x + v.y * ww.y + v.z * ww.z + v.w * ww.w;
    #pragma unroll
    for (int off = 32; off; off >>= 1) s += __shfl_xor(s, off);
    if (lane == 0) outp[row] = s + bout[0];
}

extern "C" void kernel_launch(void* const* d_in, const int* in_sizes, int n_in,
                              void* d_out, int out_size, void* d_ws, size_t ws_size,
                              hipStream_t stream)
{
    const float* x       = (const float*)d_in[0];
    const float* filters = (const float*)d_in[1];
    const float* W1      = (const float*)d_in[2];
    const float* b1      = (const float*)d_in[3];
    const float* a0      = (const float*)d_in[4];
    const float* g0      = (const float*)d_in[5];
    const float* be0     = (const float*)d_in[6];
    const float* Wc1     = (const float*)d_in[7];
    const float* bc1     = (const float*)d_in[8];
    const float* Wc2     = (const float*)d_in[9];
    const float* bc2     = (const float*)d_in[10];
    const float* Wc3     = (const float*)d_in[11];
    const float* bc3     = (const float*)d_in[12];
    const float* Wcat    = (const float*)d_in[13];
    const float* bcat    = (const float*)d_in[14];
    const float* g1      = (const float*)d_in[15];
    const float* be1     = (const float*)d_in[16];
    const float* Wf1     = (const float*)d_in[17];
    const float* bf1     = (const float*)d_in[18];
    const float* af      = (const float*)d_in[19];
    const float* Wf2     = (const float*)d_in[20];
    const float* bf2     = (const float*)d_in[21];
    const float* g2      = (const float*)d_in[22];
    const float* be2     = (const float*)d_in[23];
    const float* Wout    = (const float*)d_in[24];
    const float* boutp   = (const float*)d_in[25];
    float* outf = (float*)d_out;

    float* ws    = (float*)d_ws;
    float* wceff = ws;                                   // 4*96*256 = 98304 floats
    float* bceff = ws + 98304;                           // 384 floats
    float* bufO  = ws + 98688;                           // B*256 (current "out")
    float* bufT  = bufO + (size_t)B_ROWS * H;            // B*256 (pre-LN temp)
    float* bufH  = bufT + (size_t)B_ROWS * H;            // B*256 (xcat / h)

    dim3 blk(256);
    precompute_wceff<<<dim3(384), blk, 0, stream>>>(filters, Wc1, Wc2, Wc3,
                                                    bc1, bc2, bc3, wceff, bceff);

    dim3 g256(B_ROWS / BM, H / BN);   // (512, 4)
    dim3 g96 (B_ROWS / BM, 2);        // N=96 fits in 2 BN-tiles
    dim3 gln (B_ROWS / 4);

    // out = ln(prelu(x @ W1.T + b1, a0), g0, be0)
    gemm_nt<<<g256, blk, 0, stream>>>(x, W1, b1, nullptr, bufT, H, 128, 1, a0);
    ln_rows<<<gln, blk, 0, stream>>>(bufT, bufO, g0, be0);

    for (int i = 0; i < NBLK; ++i) {
        // xcat = lrelu(out @ Wceff_i^T + bceff_i, 0.1)          (B,96)
        gemm_nt<<<g96, blk, 0, stream>>>(bufO, wceff + i * 96 * H, bceff + i * 96,
                                         nullptr, bufH, 96, H, 2, nullptr);
        // tmp = xcat @ Wcat_i^T + bcat_i + out ; out = ln(tmp, g1, be1)
        gemm_nt<<<g256, blk, 0, stream>>>(bufH, Wcat + (size_t)i * H * 96, bcat + i * H,
                                          bufO, bufT, H, 96, 0, nullptr);
        ln_rows<<<gln, blk, 0, stream>>>(bufT, bufO, g1 + i * H, be1 + i * H);
        // h = prelu(out @ Wf1_i^T + bf1_i, af_i)
        gemm_nt<<<g256, blk, 0, stream>>>(bufO, Wf1 + (size_t)i * H * H, bf1 + i * H,
                                          nullptr, bufH, H, H, 1, af + i);
        // tmp = h @ Wf2_i^T + bf2_i + out ; out = ln(tmp, g2, be2)
        gemm_nt<<<g256, blk, 0, stream>>>(bufH, Wf2 + (size_t)i * H * H, bf2 + i * H,
                                          bufO, bufT, H, H, 0, nullptr);
        ln_rows<<<gln, blk, 0, stream>>>(bufT, bufO, g2 + i * H, be2 + i * H);
    }

    matvec_out<<<gln, blk, 0, stream>>>(bufO, Wout, boutp, outf);
}

// Round 2
// 259.384 us; speedup vs baseline: 3.9142x; 3.9142x over previous
//
#include <hip/hip_runtime.h>

#define B_ROWS 32768
#define H 256

typedef __attribute__((ext_vector_type(8))) short bf16x8;
typedef __attribute__((ext_vector_type(4))) float f32x4;

__device__ __forceinline__ float bf2f(unsigned short u) {
    union { unsigned u; float f; } x; x.u = (unsigned)u << 16; return x.f;
}
__device__ __forceinline__ unsigned short f2bf(float f) {
    union { float f; unsigned u; } x; x.f = f;
    unsigned r = x.u + 0x7fffu + ((x.u >> 16) & 1u);
    return (unsigned short)(r >> 16);
}

// ---------------------------------------------------------------------------
// Fused bf16 MFMA GEMM: out[M,BN](bf16) = LN?( act( A[M,K] @ W[BN,K]^T + bias ) + res )
// BM=32 rows/block, BN = full output width (so LN fuses in-epilogue).
// A,W bf16 K-contig. Staging: global_load_lds w16, XOR-swizzled source.
// actmode: 0 none, 1 prelu(*alpha_ptr), 2 lrelu(0.1). act applied BEFORE res/LN.
// ---------------------------------------------------------------------------
template<int BN>
__global__ __launch_bounds__(256) void gemm_fused(
    const unsigned short* __restrict__ A, int K,
    const unsigned short* __restrict__ W,
    const float* __restrict__ bias,
    const unsigned short* __restrict__ res,         // [M][256] or null
    const float* __restrict__ lng, const float* __restrict__ lnb,  // LN or null
    unsigned short* __restrict__ out, int ldo,
    int actmode, const float* __restrict__ alpha_ptr)
{
    constexpr int NT  = BN / 32;        // n-tiles (16 wide) per wave
    constexpr int ACH = 4;              // A-tile chunks of 1KB (32*128B)
    constexpr int CH  = ACH + BN / 8;   // + W-tile chunks (BN*128B/1024)
    constexpr int LNW = BN + 4;
    __shared__ char smem[(32 + BN) * 128];

    const int tid  = threadIdx.x;
    const int lane = tid & 63;
    const int wave = tid >> 6;
    const int wm   = wave >> 1;         // 2x2 wave grid: 16 rows x BN/2 cols each
    const int wn   = wave & 1;
    const int bm   = blockIdx.x * 32;

    f32x4 acc[NT];
    #pragma unroll
    for (int i = 0; i < NT; ++i) acc[i] = (f32x4){0.f, 0.f, 0.f, 0.f};

    const int rloc = lane >> 3;         // row-in-chunk
    const int off  = (lane & 7) << 4;   // 16B slot in 128B row

    for (int k0 = 0; k0 < K; k0 += 64) {
        #pragma unroll
        for (int c2 = 0; c2 < CH / 4; ++c2) {
            const int c = wave + c2 * 4;
            const char* src;
            if (c < ACH) {
                int r = c * 8 + rloc;                       // 0..31
                int offs = off ^ ((r & 7) << 4);            // pre-swizzle source
                src = (const char*)A + ((size_t)(bm + r) * K + k0) * 2 + offs;
            } else {
                int r = (c - ACH) * 8 + rloc;               // 0..BN-1
                int offs = off ^ ((r & 7) << 4);
                src = (const char*)W + ((size_t)r * K + k0) * 2 + offs;
            }
            __builtin_amdgcn_global_load_lds(
                (const __attribute__((address_space(1))) void*)src,
                (__attribute__((address_space(3))) void*)(smem + c * 1024),
                16, 0, 0);
        }
        __syncthreads();

        #pragma unroll
        for (int s = 0; s < 2; ++s) {
            const int arow = wm * 16 + (lane & 15);
            const int kb   = s * 64 + (lane >> 4) * 16;
            bf16x8 aF = *(const bf16x8*)(smem + arow * 128 + (kb ^ ((arow & 7) << 4)));
            #pragma unroll
            for (int nt = 0; nt < NT; ++nt) {
                const int wrow = wn * (BN / 2) + nt * 16 + (lane & 15);
                bf16x8 bF = *(const bf16x8*)(smem + 4096 + wrow * 128 + (kb ^ ((wrow & 7) << 4)));
                acc[nt] = __builtin_amdgcn_mfma_f32_16x16x32_bf16(aF, bF, acc[nt], 0, 0, 0);
            }
        }
        __syncthreads();
    }

    // ---- epilogue: bias + act -> f32 LDS tile ----
    float* fbuf = (float*)smem;
    const float alpha = (actmode == 1) ? *alpha_ptr : 0.1f;
    #pragma unroll
    for (int nt = 0; nt < NT; ++nt) {
        const int col = wn * (BN / 2) + nt * 16 + (lane & 15);
        const float bs = bias[col];
        #pragma unroll
        for (int r = 0; r < 4; ++r) {
            float v = acc[nt][r] + bs;
            if (actmode) v = (v >= 0.f) ? v : alpha * v;
            fbuf[(wm * 16 + (lane >> 4) * 4 + r) * LNW + col] = v;
        }
    }
    __syncthreads();

    // ---- output pass: (+res) -> LN? -> bf16 store, one wave per row ----
    constexpr int VEC = BN / 64;
    float gg[VEC], bb[VEC];
    if (lng) {
        #pragma unroll
        for (int v = 0; v < VEC; ++v) { gg[v] = lng[lane * VEC + v]; bb[v] = lnb[lane * VEC + v]; }
    }
    for (int rr = wave * 8; rr < wave * 8 + 8; ++rr) {
        float vv[VEC];
        #pragma unroll
        for (int v = 0; v < VEC; ++v) vv[v] = fbuf[rr * LNW + lane * VEC + v];
        if (res) {
            if constexpr (VEC == 4) {
                ushort4 rv = *(const ushort4*)(res + (size_t)(bm + rr) * H + lane * 4);
                vv[0] += bf2f(rv.x); vv[1] += bf2f(rv.y); vv[2] += bf2f(rv.z); vv[3] += bf2f(rv.w);
            }
        }
        float o[VEC];
        if (lng) {
            float s = 0.f;
            #pragma unroll
            for (int v = 0; v < VEC; ++v) s += vv[v];
            #pragma unroll
            for (int m = 32; m; m >>= 1) s += __shfl_xor(s, m);
            const float mean = s * (1.f / BN);
            float d[VEC], q = 0.f;
            #pragma unroll
            for (int v = 0; v < VEC; ++v) { d[v] = vv[v] - mean; q += d[v] * d[v]; }
            #pragma unroll
            for (int m = 32; m; m >>= 1) q += __shfl_xor(q, m);
            const float rstd = rsqrtf(q * (1.f / BN) + 1e-5f);
            #pragma unroll
            for (int v = 0; v < VEC; ++v) o[v] = d[v] * rstd * gg[v] + bb[v];
        } else {
            #pragma unroll
            for (int v = 0; v < VEC; ++v) o[v] = vv[v];
        }
        unsigned short* op = out + (size_t)(bm + rr) * ldo + lane * VEC;
        if constexpr (VEC == 4) {
            ushort4 ov = { f2bf(o[0]), f2bf(o[1]), f2bf(o[2]), f2bf(o[3]) };
            *(ushort4*)op = ov;
        } else {
            ushort2 ov = { f2bf(o[0]), f2bf(o[1]) };
            *(ushort2*)op = ov;
        }
    }
}

// ---------------------------------------------------------------------------
__global__ __launch_bounds__(256) void cvt_x_kernel(const float4* __restrict__ x,
                                                    ushort4* __restrict__ xb)
{
    int i = blockIdx.x * 256 + threadIdx.x;     // exactly 1048576
    float4 v = x[i];
    ushort4 o = { f2bf(v.x), f2bf(v.y), f2bf(v.z), f2bf(v.w) };
    xb[i] = o;
}

// Convert W1/Wf1/Wf2 to bf16; Wcat [4][256][96] -> bf16 padded [4][256][128]
__global__ __launch_bounds__(256) void cvt_w_kernel(
    const float* __restrict__ W1, const float* __restrict__ Wf1,
    const float* __restrict__ Wf2, const float* __restrict__ Wcat,
    unsigned short* __restrict__ W1b, unsigned short* __restrict__ Wf1b,
    unsigned short* __restrict__ Wf2b, unsigned short* __restrict__ Wcatb)
{
    int idx = blockIdx.x * 256 + threadIdx.x;   // 688128 total
    if (idx < 32768) {
        W1b[idx] = f2bf(W1[idx]);
    } else if (idx < 32768 + 262144) {
        int j = idx - 32768; Wf1b[j] = f2bf(Wf1[j]);
    } else if (idx < 32768 + 524288) {
        int j = idx - 294912; Wf2b[j] = f2bf(Wf2[j]);
    } else if (idx < 688128) {
        int j = idx - 557056;                   // [4][256][128]
        int k = j & 127, n = (j >> 7) & 255, i4 = j >> 15;
        Wcatb[j] = (k < 96) ? f2bf(Wcat[(i4 * 256 + n) * 96 + k]) : (unsigned short)0;
    }
}

// Fold conv into GEMM weights, bf16, padded [4][128][256] (rows 96..127 zero)
__global__ __launch_bounds__(256) void wceff_kernel(
    const float* __restrict__ filters,
    const float* __restrict__ Wc1, const float* __restrict__ Wc2, const float* __restrict__ Wc3,
    const float* __restrict__ bc1, const float* __restrict__ bc2, const float* __restrict__ bc3,
    unsigned short* __restrict__ wceffb, float* __restrict__ bceff)
{
    int idx = blockIdx.x * 256 + threadIdx.x;   // 131072 total
    if (idx >= 4 * 128 * 256) return;
    int h = idx & 255, j = (idx >> 8) & 127, i = idx >> 15;
    if (j < 96) {
        int c = j >> 5, jj = j & 31;
        const float* Wc = (c == 0) ? Wc1 : (c == 1) ? Wc2 : Wc3;
        const float* f  = filters + c * 25;
        float acc = 0.f;
        #pragma unroll
        for (int k = 0; k < 25; ++k) {
            int hh = h + 12 - k;
            if (hh >= 0 && hh < H) acc += f[k] * Wc[(i * 32 + jj) * H + hh];
        }
        wceffb[idx] = f2bf(acc);
        if (h == 0) {
            const float* bc = (c == 0) ? bc1 : (c == 1) ? bc2 : bc3;
            bceff[i * 128 + j] = bc[i * 32 + jj];
        }
    } else {
        wceffb[idx] = 0;
        if (h == 0) bceff[i * 128 + j] = 0.f;
    }
}

__global__ __launch_bounds__(256) void matvec_out(
    const unsigned short* __restrict__ in, const float* __restrict__ w,
    const float* __restrict__ bout, float* __restrict__ outp)
{
    const int lane = threadIdx.x & 63;
    const int row  = blockIdx.x * 4 + (threadIdx.x >> 6);
    ushort4 v  = *(const ushort4*)(in + (size_t)row * H + lane * 4);
    float4 ww  = *(const float4*)(w + lane * 4);
    float s = bf2f(v.x) * ww.x + bf2f(v.y) * ww.y + bf2f(v.z) * ww.z + bf2f(v.w) * ww.w;
    #pragma unroll
    for (int m = 32; m; m >>= 1) s += __shfl_xor(s, m);
    if (lane == 0) outp[row] = s + bout[0];
}

extern "C" void kernel_launch(void* const* d_in, const int* in_sizes, int n_in,
                              void* d_out, int out_size, void* d_ws, size_t ws_size,
                              hipStream_t stream)
{
    const float* x       = (const float*)d_in[0];
    const float* filters = (const float*)d_in[1];
    const float* W1      = (const float*)d_in[2];
    const float* b1      = (const float*)d_in[3];
    const float* a0      = (const float*)d_in[4];
    const float* g0      = (const float*)d_in[5];
    const float* be0     = (const float*)d_in[6];
    const float* Wc1     = (const float*)d_in[7];
    const float* bc1     = (const float*)d_in[8];
    const float* Wc2     = (const float*)d_in[9];
    const float* bc2     = (const float*)d_in[10];
    const float* Wc3     = (const float*)d_in[11];
    const float* bc3     = (const float*)d_in[12];
    const float* Wcat    = (const float*)d_in[13];
    const float* bcat    = (const float*)d_in[14];
    const float* g1      = (const float*)d_in[15];
    const float* be1     = (const float*)d_in[16];
    const float* Wf1     = (const float*)d_in[17];
    const float* bf1     = (const float*)d_in[18];
    const float* af      = (const float*)d_in[19];
    const float* Wf2     = (const float*)d_in[20];
    const float* bf2     = (const float*)d_in[21];
    const float* g2      = (const float*)d_in[22];
    const float* be2     = (const float*)d_in[23];
    const float* Wout    = (const float*)d_in[24];
    const float* boutp   = (const float*)d_in[25];
    float* outf = (float*)d_out;

    unsigned short* p = (unsigned short*)d_ws;
    unsigned short* x_bf   = p; p += (size_t)B_ROWS * 128;
    unsigned short* act0   = p; p += (size_t)B_ROWS * 256;
    unsigned short* act1   = p; p += (size_t)B_ROWS * 256;
    unsigned short* hbuf   = p; p += (size_t)B_ROWS * 256;
    unsigned short* xcat   = p; p += (size_t)B_ROWS * 128;
    unsigned short* W1b    = p; p += 256 * 128;
    unsigned short* wceffb = p; p += 4 * 128 * 256;
    unsigned short* Wcatb  = p; p += 4 * 256 * 128;
    unsigned short* Wf1b   = p; p += 4 * 256 * 256;
    unsigned short* Wf2b   = p; p += 4 * 256 * 256;
    float* bceff = (float*)p;   // 512 floats

    dim3 blk(256);
    cvt_x_kernel<<<dim3(4096), blk, 0, stream>>>((const float4*)x, (ushort4*)x_bf);
    cvt_w_kernel<<<dim3(2688), blk, 0, stream>>>(W1, Wf1, Wf2, Wcat, W1b, Wf1b, Wf2b, Wcatb);
    wceff_kernel<<<dim3(512), blk, 0, stream>>>(filters, Wc1, Wc2, Wc3, bc1, bc2, bc3,
                                                wceffb, bceff);

    dim3 gg(B_ROWS / 32);   // 1024 blocks

    // out = ln(prelu(x @ W1.T + b1, a0), g0, be0)
    gemm_fused<256><<<gg, blk, 0, stream>>>(x_bf, 128, W1b, b1, nullptr, g0, be0,
                                            act0, 256, 1, a0);
    for (int i = 0; i < 4; ++i) {
        // xcat = lrelu(out @ Wceff^T + bceff, 0.1)   [cols 96..127 land 0]
        gemm_fused<128><<<gg, blk, 0, stream>>>(act0, 256, wceffb + i * 128 * 256,
                                                bceff + i * 128, nullptr, nullptr, nullptr,
                                                xcat, 128, 2, nullptr);
        // out = ln(xcat @ Wcat^T + bcat + out)
        gemm_fused<256><<<gg, blk, 0, stream>>>(xcat, 128, Wcatb + i * 256 * 128,
                                                bcat + i * 256, act0, g1 + i * 256, be1 + i * 256,
                                                act1, 256, 0, nullptr);
        // h = prelu(out @ Wf1^T + bf1, af[i])
        gemm_fused<256><<<gg, blk, 0, stream>>>(act1, 256, Wf1b + i * 256 * 256,
                                                bf1 + i * 256, nullptr, nullptr, nullptr,
                                                hbuf, 256, 1, af + i);
        // out = ln(h @ Wf2^T + bf2 + out)
        gemm_fused<256><<<gg, blk, 0, stream>>>(hbuf, 256, Wf2b + i * 256 * 256,
                                                bf2 + i * 256, act1, g2 + i * 256, be2 + i * 256,
                                                act0, 256, 0, nullptr);
    }
    matvec_out<<<dim3(B_ROWS / 4), blk, 0, stream>>>(act0, Wout, boutp, outf);
}

// Round 4
// 141.680 us; speedup vs baseline: 7.1660x; 1.8308x over previous
//
#include <hip/hip_runtime.h>

typedef __attribute__((ext_vector_type(8))) short bf16x8;
typedef __attribute__((ext_vector_type(4))) float f32x4;

__device__ __forceinline__ float bf2f(unsigned short u) {
    union { unsigned u; float f; } x; x.u = (unsigned)u << 16; return x.f;
}
__device__ __forceinline__ unsigned short f2bf(float f) {
    union { float f; unsigned u; } x; x.f = f;
    unsigned r = x.u + 0x7fffu + ((x.u >> 16) & 1u);
    return (unsigned short)(r >> 16);
}

#define GLDS(src, dst) __builtin_amdgcn_global_load_lds( \
    (const __attribute__((address_space(1))) void*)(src), \
    (__attribute__((address_space(3))) void*)(dst), 16, 0, 0)

// ---------------------------------------------------------------------------
// Weight prep: convert to bf16, fold conv into wceff, pad.
// Layout (elements):
//   W1b    [256][256]  (k>=128 zero)            @ 0        (65536)
//   wceffb [4][128][256] (n>=96 rows zero)      @ 65536    (131072)
//   Wcatb  [4][256][256] (k>=96 zero)           @ 196608   (262144)
//   Wf1b   [4][256][256]                        @ 458752   (262144)
//   Wf2b   [4][256][256]                        @ 720896   (262144)
//   bceff  [4][128] f32                         @ 983040 shorts
// Total threads: 983040 = 3840 * 256.
// ---------------------------------------------------------------------------
__global__ __launch_bounds__(256) void prep(
    const float* __restrict__ filters,
    const float* __restrict__ Wc1, const float* __restrict__ Wc2, const float* __restrict__ Wc3,
    const float* __restrict__ bc1, const float* __restrict__ bc2, const float* __restrict__ bc3,
    const float* __restrict__ W1, const float* __restrict__ Wcat,
    const float* __restrict__ Wf1, const float* __restrict__ Wf2,
    unsigned short* __restrict__ W1b, unsigned short* __restrict__ wceffb,
    float* __restrict__ bceff, unsigned short* __restrict__ Wcatb,
    unsigned short* __restrict__ Wf1b, unsigned short* __restrict__ Wf2b)
{
    int idx = blockIdx.x * 256 + threadIdx.x;
    if (idx < 65536) {                       // W1b [256][256], k>=128 zero
        int n = idx >> 8, k = idx & 255;
        W1b[idx] = (k < 128) ? f2bf(W1[n * 128 + k]) : (unsigned short)0;
    } else if (idx < 196608) {               // wceffb [4][128][256], n>=96 zero
        int j = idx - 65536;
        int i = j >> 15, n = (j >> 8) & 127, h = j & 255;
        if (n < 96) {
            int c = n >> 5, jj = n & 31;
            const float* Wc = (c == 0) ? Wc1 : (c == 1) ? Wc2 : Wc3;
            const float* f  = filters + c * 25;
            float acc = 0.f;
            #pragma unroll
            for (int k = 0; k < 25; ++k) {
                int hh = h + 12 - k;
                if (hh >= 0 && hh < 256) acc += f[k] * Wc[(i * 32 + jj) * 256 + hh];
            }
            wceffb[j] = f2bf(acc);
            if (h == 0) {
                const float* bc = (c == 0) ? bc1 : (c == 1) ? bc2 : bc3;
                bceff[i * 128 + n] = bc[i * 32 + jj];
            }
        } else {
            wceffb[j] = 0;
            if (h == 0) bceff[i * 128 + n] = 0.f;
        }
    } else if (idx < 458752) {               // Wcatb [4][256][256], k>=96 zero
        int j = idx - 196608;
        int i = j >> 16, rem = j & 65535, n = rem >> 8, k = rem & 255;
        Wcatb[j] = (k < 96) ? f2bf(Wcat[(i * 256 + n) * 96 + k]) : (unsigned short)0;
    } else if (idx < 720896) {               // Wf1b [4][256][256]
        int j = idx - 458752;
        Wf1b[j] = f2bf(Wf1[j]);
    } else if (idx < 983040) {               // Wf2b [4][256][256]
        int j = idx - 720896;
        Wf2b[j] = f2bf(Wf2[j]);
    }
}

// ---------------------------------------------------------------------------
// One GEMM stage inside the mega-kernel.
// acc = mfma(A=W_frag, B=act_frag): D col(lane&15) = batch row m,
// D row((lane>>4)*4+reg) = output channel n.  (layout verified in R2)
// act/W LDS = 1KB fragment tiles [4 kblk][16 row][8 k], slot = lane*16B.
// NKC = K/32 chunks, NWT = n-tiles per wave (N = NWT*64).
// ---------------------------------------------------------------------------
template<int NKC, int NWT>
__device__ __forceinline__ void gemm_stage(
    const unsigned short* __restrict__ Wg,   // [NT*16][256] padded rows
    const float* __restrict__ bias,
    const unsigned short* actIn, unsigned short* actOut,
    unsigned short* wlds,
    int actmode, const float* alphap,
    const unsigned short* resbuf,            // null if no residual
    const float* g, const float* be,         // null if no LN (N=256 when LN)
    int finaldot, const float* Wout, const float* boutp, float* outg, int rowbase)
{
    constexpr int NT = NWT * 4;              // total n-tiles (N/16)
    const int tid  = threadIdx.x;
    const int lane = tid & 63;
    const int wave = tid >> 6;
    const int wm   = wave >> 2;              // 0..1  (64 rows each)
    const int wn   = wave & 3;               // 0..3  (NWT*16 cols each)
    const int l15  = lane & 15;
    const int hi   = lane >> 4;

    f32x4 acc[4][NWT];
    #pragma unroll
    for (int mt = 0; mt < 4; ++mt)
        #pragma unroll
        for (int nt = 0; nt < NWT; ++nt) acc[mt][nt] = (f32x4){0.f, 0.f, 0.f, 0.f};

    // stage chunk 0
    #pragma unroll
    for (int tt = 0; tt < NT / 8; ++tt) {
        const int t = wave + tt * 8;
        GLDS(Wg + (t * 16 + l15) * 256 + hi * 8, wlds + t * 512);
    }
    __syncthreads();

    for (int kc = 0; kc < NKC; ++kc) {
        const int cur = (kc & 1) * 8192;
        if (kc + 1 < NKC) {
            const int nxt = ((kc + 1) & 1) * 8192;
            #pragma unroll
            for (int tt = 0; tt < NT / 8; ++tt) {
                const int t = wave + tt * 8;
                GLDS(Wg + (t * 16 + l15) * 256 + (kc + 1) * 32 + hi * 8,
                     wlds + nxt + t * 512);
            }
        }
        bf16x8 bfr[4], afr[NWT];
        #pragma unroll
        for (int mt = 0; mt < 4; ++mt)
            bfr[mt] = *(const bf16x8*)(actIn + ((wm * 4 + mt) * 8 + kc) * 512 + lane * 8);
        #pragma unroll
        for (int nt = 0; nt < NWT; ++nt)
            afr[nt] = *(const bf16x8*)(wlds + cur + (wn * NWT + nt) * 512 + lane * 8);
        #pragma unroll
        for (int mt = 0; mt < 4; ++mt)
            #pragma unroll
            for (int nt = 0; nt < NWT; ++nt)
                acc[mt][nt] = __builtin_amdgcn_mfma_f32_16x16x32_bf16(
                    afr[nt], bfr[mt], acc[mt][nt], 0, 0, 0);
        __syncthreads();   // next chunk staged (drains vmcnt) + LDS reads done
    }

    // ---- epilogue: bias -> act -> res -> (LN) -> store/dot ----
    const float alpha = alphap ? alphap[0] : 0.1f;
    float vv[4][NWT][4];
    #pragma unroll
    for (int mt = 0; mt < 4; ++mt) {
        #pragma unroll
        for (int nt = 0; nt < NWT; ++nt) {
            const int nb = wn * (NWT * 16) + nt * 16 + hi * 4;
            const float4 bs = *(const float4*)(bias + nb);
            float t0 = acc[mt][nt][0] + bs.x;
            float t1 = acc[mt][nt][1] + bs.y;
            float t2 = acc[mt][nt][2] + bs.z;
            float t3 = acc[mt][nt][3] + bs.w;
            if (actmode) {
                t0 = t0 >= 0.f ? t0 : alpha * t0;
                t1 = t1 >= 0.f ? t1 : alpha * t1;
                t2 = t2 >= 0.f ? t2 : alpha * t2;
                t3 = t3 >= 0.f ? t3 : alpha * t3;
            }
            if (resbuf) {
                const int ro = ((wm * 4 + mt) * 8 + (nb >> 5)) * 512
                             + (l15 + ((nb >> 3) & 3) * 16) * 8 + (nb & 7);
                const ushort4 rv = *(const ushort4*)(resbuf + ro);
                t0 += bf2f(rv.x); t1 += bf2f(rv.y); t2 += bf2f(rv.z); t3 += bf2f(rv.w);
            }
            vv[mt][nt][0] = t0; vv[mt][nt][1] = t1;
            vv[mt][nt][2] = t2; vv[mt][nt][3] = t3;
        }
    }

    float* lnred = (float*)wlds;             // 4KB scratch, W buffers dead now
    float mean[4], rstd[4];
    if (g) {
        #pragma unroll
        for (int mt = 0; mt < 4; ++mt) {
            float s = 0.f, q = 0.f;
            #pragma unroll
            for (int nt = 0; nt < NWT; ++nt)
                #pragma unroll
                for (int r = 0; r < 4; ++r) { const float v = vv[mt][nt][r]; s += v; q += v * v; }
            s += __shfl_xor(s, 16); s += __shfl_xor(s, 32);
            q += __shfl_xor(q, 16); q += __shfl_xor(q, 32);
            if (hi == 0)
                *(float2*)(lnred + (wm * 64 + mt * 16 + l15) * 8 + wn * 2) = make_float2(s, q);
        }
        __syncthreads();
        #pragma unroll
        for (int mt = 0; mt < 4; ++mt) {
            const int m = wm * 64 + mt * 16 + l15;
            const float4 p0 = *(const float4*)(lnred + m * 8);
            const float4 p1 = *(const float4*)(lnred + m * 8 + 4);
            const float s = p0.x + p0.z + p1.x + p1.z;
            const float q = p0.y + p0.w + p1.y + p1.w;
            const float mu = s * (1.f / 256.f);
            mean[mt] = mu;
            rstd[mt] = rsqrtf(q * (1.f / 256.f) - mu * mu + 1e-5f);
        }
    }

    float* dotp = (float*)wlds + 2048;       // disjoint from lnred
    #pragma unroll
    for (int mt = 0; mt < 4; ++mt) {
        float dp = 0.f;
        #pragma unroll
        for (int nt = 0; nt < NWT; ++nt) {
            const int nb = wn * (NWT * 16) + nt * 16 + hi * 4;
            float o0 = vv[mt][nt][0], o1 = vv[mt][nt][1], o2 = vv[mt][nt][2], o3 = vv[mt][nt][3];
            if (g) {
                const float4 gv = *(const float4*)(g + nb);
                const float4 bv = *(const float4*)(be + nb);
                o0 = (o0 - mean[mt]) * rstd[mt] * gv.x + bv.x;
                o1 = (o1 - mean[mt]) * rstd[mt] * gv.y + bv.y;
                o2 = (o2 - mean[mt]) * rstd[mt] * gv.z + bv.z;
                o3 = (o3 - mean[mt]) * rstd[mt] * gv.w + bv.w;
            }
            if (!finaldot) {
                const ushort4 ov = {f2bf(o0), f2bf(o1), f2bf(o2), f2bf(o3)};
                *(ushort4*)(actOut + ((wm * 4 + mt) * 8 + (nb >> 5)) * 512
                            + (l15 + ((nb >> 3) & 3) * 16) * 8 + (nb & 7)) = ov;
            } else {
                const float4 wv = *(const float4*)(Wout + nb);
                dp += o0 * wv.x + o1 * wv.y + o2 * wv.z + o3 * wv.w;
            }
        }
        if (finaldot) {
            dp += __shfl_xor(dp, 16); dp += __shfl_xor(dp, 32);
            if (hi == 0) dotp[(wm * 64 + mt * 16 + l15) * 4 + wn] = dp;
        }
    }
    if (finaldot) {
        __syncthreads();
        if (tid < 128) {
            const float4 pp = *(const float4*)(dotp + tid * 4);
            outg[rowbase + tid] = pp.x + pp.y + pp.z + pp.w + boutp[0];
        }
    }
    __syncthreads();
}

// ---------------------------------------------------------------------------
// Persistent mega-kernel: 256 blocks x 512 threads, 128 rows per block,
// all 17 stages with activations LDS-resident. LDS = 64+64+32 = 160KB.
// ---------------------------------------------------------------------------
__global__ __launch_bounds__(512, 2) void mega(
    const float* __restrict__ x,
    const unsigned short* __restrict__ W1b, const float* __restrict__ b1,
    const float* __restrict__ a0, const float* __restrict__ g0, const float* __restrict__ be0,
    const unsigned short* __restrict__ wceffb, const float* __restrict__ bceff,
    const unsigned short* __restrict__ Wcatb, const float* __restrict__ bcat,
    const float* __restrict__ g1, const float* __restrict__ be1,
    const unsigned short* __restrict__ Wf1b, const float* __restrict__ bf1,
    const float* __restrict__ af,
    const unsigned short* __restrict__ Wf2b, const float* __restrict__ bf2,
    const float* __restrict__ g2, const float* __restrict__ be2,
    const float* __restrict__ Wout, const float* __restrict__ boutp,
    float* __restrict__ outg)
{
    __shared__ __align__(16) unsigned short actA[32768];   // 64KB
    __shared__ __align__(16) unsigned short actB[32768];   // 64KB
    __shared__ __align__(16) unsigned short wlds[16384];   // 2 x 16KB dbuf

    const int tid = threadIdx.x;
    const int rowbase = blockIdx.x * 128;

    // phase 0: stage x (f32) -> actB fragment tiles (bf16), K=128
    {
        const int r = tid >> 2, q = tid & 3;
        const float* xp = x + (size_t)(rowbase + r) * 128 + q * 32;
        #pragma unroll
        for (int gi = 0; gi < 8; ++gi) {
            const float4 xv = *(const float4*)(xp + gi * 4);
            const int j = q * 32 + gi * 4;
            const ushort4 o = {f2bf(xv.x), f2bf(xv.y), f2bf(xv.z), f2bf(xv.w)};
            *(ushort4*)(actB + ((r >> 4) * 8 + (j >> 5)) * 512
                        + ((r & 15) + ((j >> 3) & 3) * 16) * 8 + (j & 7)) = o;
        }
        __syncthreads();
    }

    // out = ln(prelu(x @ W1^T + b1, a0), g0, be0)        B -> A
    gemm_stage<4, 4>(W1b, b1, actB, actA, wlds, 1, a0, nullptr, g0, be0,
                     0, nullptr, nullptr, nullptr, 0);

    for (int it = 0; it < 4; ++it) {
        // xcat = lrelu(out @ wceff^T + bceff, 0.1)       A -> B  (N=128)
        gemm_stage<8, 2>(wceffb + it * 32768, bceff + it * 128, actA, actB, wlds,
                         2, nullptr, nullptr, nullptr, nullptr, 0, nullptr, nullptr, nullptr, 0);
        // out = ln(xcat @ Wcat^T + bcat + out)           B -> A (res A, safe)
        gemm_stage<4, 4>(Wcatb + it * 65536, bcat + it * 256, actB, actA, wlds,
                         0, nullptr, actA, g1 + it * 256, be1 + it * 256,
                         0, nullptr, nullptr, nullptr, 0);
        // h = prelu(out @ Wf1^T + bf1, af[it])           A -> B
        gemm_stage<8, 4>(Wf1b + it * 65536, bf1 + it * 256, actA, actB, wlds,
                         1, af + it, nullptr, nullptr, nullptr, 0, nullptr, nullptr, nullptr, 0);
        // out = ln(h @ Wf2^T + bf2 + out); last iter fuses final matvec
        gemm_stage<8, 4>(Wf2b + it * 65536, bf2 + it * 256, actB, actA, wlds,
                         0, nullptr, actA, g2 + it * 256, be2 + it * 256,
                         (it == 3) ? 1 : 0, Wout, boutp, outg, rowbase);
    }
}

extern "C" void kernel_launch(void* const* d_in, const int* in_sizes, int n_in,
                              void* d_out, int out_size, void* d_ws, size_t ws_size,
                              hipStream_t stream)
{
    const float* x       = (const float*)d_in[0];
    const float* filters = (const float*)d_in[1];
    const float* W1      = (const float*)d_in[2];
    const float* b1      = (const float*)d_in[3];
    const float* a0      = (const float*)d_in[4];
    const float* g0      = (const float*)d_in[5];
    const float* be0     = (const float*)d_in[6];
    const float* Wc1     = (const float*)d_in[7];
    const float* bc1     = (const float*)d_in[8];
    const float* Wc2     = (const float*)d_in[9];
    const float* bc2     = (const float*)d_in[10];
    const float* Wc3     = (const float*)d_in[11];
    const float* bc3     = (const float*)d_in[12];
    const float* Wcat    = (const float*)d_in[13];
    const float* bcat    = (const float*)d_in[14];
    const float* g1      = (const float*)d_in[15];
    const float* be1     = (const float*)d_in[16];
    const float* Wf1     = (const float*)d_in[17];
    const float* bf1     = (const float*)d_in[18];
    const float* af      = (const float*)d_in[19];
    const float* Wf2     = (const float*)d_in[20];
    const float* bf2     = (const float*)d_in[21];
    const float* g2      = (const float*)d_in[22];
    const float* be2     = (const float*)d_in[23];
    const float* Wout    = (const float*)d_in[24];
    const float* boutp   = (const float*)d_in[25];
    float* outf = (float*)d_out;

    unsigned short* p = (unsigned short*)d_ws;
    unsigned short* W1b    = p;              // 65536
    unsigned short* wceffb = p + 65536;      // 131072
    unsigned short* Wcatb  = p + 196608;     // 262144
    unsigned short* Wf1b   = p + 458752;     // 262144
    unsigned short* Wf2b   = p + 720896;     // 262144
    float*          bceff  = (float*)(p + 983040);  // 512 floats

    prep<<<dim3(3840), dim3(256), 0, stream>>>(
        filters, Wc1, Wc2, Wc3, bc1, bc2, bc3, W1, Wcat, Wf1, Wf2,
        W1b, wceffb, bceff, Wcatb, Wf1b, Wf2b);

    mega<<<dim3(256), dim3(512), 0, stream>>>(
        x, W1b, b1, a0, g0, be0, wceffb, bceff, Wcatb, bcat, g1, be1,
        Wf1b, bf1, af, Wf2b, bf2, g2, be2, Wout, boutp, outf);
}